// Round 4
// baseline (333.270 us; speedup 1.0000x reference)
//
#include <hip/hip_runtime.h>
#include <math.h>

#define EPSQ 1e-7f
#define TDIM 2000
#define CDIM 128
#define LDIM 200
#define SDIM 401
#define SPL  7
#define SENTE (-(1 << 30))
#define PD   12              // emission pipeline depth (rows ahead)

__device__ __forceinline__ float dpp_shr_f(float x) { // lane i <- lane i-1, lane0 <- 0
    return __int_as_float(__builtin_amdgcn_update_dpp(0, __float_as_int(x), 0x138, 0xf, 0xf, true));
}
__device__ __forceinline__ int dpp_shr_i(int x) {
    return __builtin_amdgcn_update_dpp(0, x, 0x138, 0xf, 0xf, true);
}
__device__ __forceinline__ float dpp_shl_f(float x) { // lane i <- lane i+1, lane63 <- 0
    return __int_as_float(__builtin_amdgcn_update_dpp(0, __float_as_int(x), 0x130, 0xf, 0xf, true));
}
__device__ __forceinline__ int dpp_shl_i(int x) {
    return __builtin_amdgcn_update_dpp(0, x, 0x130, 0xf, 0xf, true);
}

// per-lane block-floating-point renorm (every 4 steps); neighbor = lane-1 (alpha)
__device__ __forceinline__ void renorm_alpha(float a[SPL], int& E, float& fprev, int lane) {
    float mx = fmaxf(fmaxf(fmaxf(a[0], a[1]), fmaxf(a[2], a[3])),
                     fmaxf(fmaxf(a[4], a[5]), a[6]));
    bool zero = (mx == 0.f);
    int e = ((__float_as_int(mx) >> 23) & 0xff) - 127;
    int S_self = zero ? SENTE : (E + e);
    int S1 = dpp_shr_i(S_self);
    if (lane == 0) S1 = SENTE;
    int S2 = dpp_shr_i(S1);
    if (lane == 0) S2 = SENTE;
    int E_new = max(S_self, S1);
    int E_prevnew = max(S1, S2);
    int dg = E - E_new;
    float g = (zero || dg < -126) ? 0.f : __int_as_float((dg + 127) << 23);
#pragma unroll
    for (int j = 0; j < SPL; ++j) a[j] *= g;
    E = E_new;
    int df = E_prevnew - E_new;
    bool fz = (E_prevnew <= SENTE / 2) || (df < -126);
    if (df > 126) df = 126;
    fprev = fz ? 0.f : __int_as_float((df + 127) << 23);
}

// mirror: neighbor = lane+1 (beta)
__device__ __forceinline__ void renorm_beta(float b[SPL], int& E, float& fnext, int lane) {
    float mx = fmaxf(fmaxf(fmaxf(b[0], b[1]), fmaxf(b[2], b[3])),
                     fmaxf(fmaxf(b[4], b[5]), b[6]));
    bool zero = (mx == 0.f);
    int e = ((__float_as_int(mx) >> 23) & 0xff) - 127;
    int S_self = zero ? SENTE : (E + e);
    int S1 = dpp_shl_i(S_self);
    if (lane == 63) S1 = SENTE;
    int S2 = dpp_shl_i(S1);
    if (lane == 63) S2 = SENTE;
    int E_new = max(S_self, S1);
    int E_nextnew = max(S1, S2);
    int dg = E - E_new;
    float g = (zero || dg < -126) ? 0.f : __int_as_float((dg + 127) << 23);
#pragma unroll
    for (int j = 0; j < SPL; ++j) b[j] *= g;
    E = E_new;
    int df = E_nextnew - E_new;
    bool fz = (E_nextnew <= SENTE / 2) || (df < -126);
    if (df > 126) df = 126;
    fnext = fz ? 0.f : __int_as_float((df + 127) << 23);
}

// Build qe[0..6] from blank + 4 label values by lane parity:
//  j even: par ? L[j/2] : B ;  j odd: par ? B : L[(j-1)/2]
#define BUILD_Q(SL)                                                            \
    float Bv = QB[SL] + EPSQ;                                                  \
    float e0 = QL[SL][0] + EPSQ, e1 = QL[SL][1] + EPSQ;                        \
    float e2 = QL[SL][2] + EPSQ, e3 = QL[SL][3] + EPSQ;                        \
    float q0 = par ? e0 : Bv, q1 = par ? Bv : e0;                              \
    float q2 = par ? e1 : Bv, q3 = par ? Bv : e1;                              \
    float q4 = par ? e2 : Bv, q5 = par ? Bv : e2;                              \
    float q6 = par ? e3 : Bv;

#define RELOAD(SL, ROW)                                                        \
    {   const float* rowp = ybase + (size_t)(ROW) * CDIM;                      \
        QB[SL] = rowp[CDIM - 1];                                               \
        QL[SL][0] = rowp[offL[0]]; QL[SL][1] = rowp[offL[1]];                  \
        QL[SL][2] = rowp[offL[2]]; QL[SL][3] = rowp[offL[3]]; }

#define A_STEP(TOFF) do {                                                      \
    constexpr int SL = (1 + (TOFF)) % PD;                                      \
    const int tcur = t + (TOFF);                                               \
    BUILD_Q(SL)                                                                \
    float p6 = dpp_shr_f(a[6]) * fprev;                                        \
    float p5 = dpp_shr_f(a[5]) * fprev;                                        \
    float n0 = fmaf(skipf[0], p5,   a[0] + p6)   * q0;                         \
    float n1 = fmaf(skipf[1], p6,   a[1] + a[0]) * q1;                         \
    float n2 = fmaf(skipf[2], a[0], a[2] + a[1]) * q2;                         \
    float n3 = fmaf(skipf[3], a[1], a[3] + a[2]) * q3;                         \
    float n4 = fmaf(skipf[4], a[2], a[4] + a[3]) * q4;                         \
    float n5 = fmaf(skipf[5], a[3], a[5] + a[4]) * q5;                         \
    float n6 = fmaf(skipf[6], a[4], a[6] + a[5]) * q6;                         \
    a[0]=n0; a[1]=n1; a[2]=n2; a[3]=n3; a[4]=n4; a[5]=n5; a[6]=n6;             \
    if (tcur == m) {                                                           \
        _Pragma("unroll")                                                      \
        for (int j = 0; j < SPL; ++j) ac[j] = a[j];                            \
        Eac = E;                                                               \
    }                                                                          \
    RELOAD(SL, tcur + PD)                                                      \
} while (0);

#define B_STEP(SOFF) do {                                                      \
    constexpr int SL = (SOFF) % PD;                                            \
    const int scur = s + (SOFF);                                               \
    BUILD_Q(SL)                                                                \
    float c0 = bb[0]*q0, c1 = bb[1]*q1, c2 = bb[2]*q2, c3 = bb[3]*q3;          \
    float c4 = bb[4]*q4, c5 = bb[5]*q5, c6 = bb[6]*q6;                         \
    float cn0 = dpp_shl_f(c0) * fnext;                                         \
    float cn1 = dpp_shl_f(c1) * fnext;                                         \
    bb[0] = fmaf(skb[0], c2, c0 + c1);                                         \
    bb[1] = fmaf(skb[1], c3, c1 + c2);                                         \
    bb[2] = fmaf(skb[2], c4, c2 + c3);                                         \
    bb[3] = fmaf(skb[3], c5, c3 + c4);                                         \
    bb[4] = fmaf(skb[4], c6, c4 + c5);                                         \
    bb[5] = fmaf(skb[5], cn0, c5 + c6);                                        \
    bb[6] = fmaf(skb[6], cn1, c6 + cn0);                                       \
    if (scur == scap) {                                                        \
        _Pragma("unroll")                                                      \
        for (int j = 0; j < SPL; ++j) bc[j] = bb[j];                           \
        Ebc = E;                                                               \
    }                                                                          \
    RELOAD(SL, t0 - scur - PD)                                                 \
} while (0);

__global__ void __launch_bounds__(64)
__attribute__((amdgpu_waves_per_eu(1, 1)))
ctc_main(const float* __restrict__ y_pred,
         const int* __restrict__ labels,
         const int* __restrict__ feat_lens,
         const int* __restrict__ label_lens,
         float* __restrict__ ws)           // 1024 floats per batch item
{
    const int b = blockIdx.x >> 1;
    const int role = blockIdx.x & 1;       // 0 = alpha, 1 = beta
    const int lane = threadIdx.x;

    int f = feat_lens[b];
    f = (f + 1) >> 1; f = (f + 1) >> 1;
    const int Tbm1 = f - 1;
    const int m = f >> 1;                  // alpha: steps 1..m; beta: rows Tbm1..m+1
    const int llen = label_lens[b];
    const int i1 = 2 * llen - 1, i2 = 2 * llen;

    const float* ybase = y_pred + (size_t)b * TDIM * CDIM;
    const int* labrow = labels + b * LDIM;

    // ---- per-lane constants: labels LA[k0-1 .. k0+3], offsets, skip flags ----
    const int s0 = lane * SPL;
    const int k0 = s0 >> 1;
    const bool par = (lane & 1) != 0;      // parity of s0
    int LA[5];
#pragma unroll
    for (int i = 0; i < 5; ++i) {
        int k = k0 - 1 + i;
        if (k < 0) k = 0;
        if (k > LDIM - 1) k = LDIM - 1;
        LA[i] = labrow[k];
    }
    int offL[4];
#pragma unroll
    for (int i = 0; i < 4; ++i) offL[i] = LA[i + 1];   // class index in [0,126]

    float skipf[SPL];
#pragma unroll
    for (int j = 0; j < SPL; ++j) {
        int s = s0 + j;
        float sk = 0.f;
        bool emit = (s < SDIM) && ((s & 1) != 0);
        if (emit) {
            int idx = (j >> 1) + 1;        // LA[idx] = labs[k], LA[idx-1] = labs[k-1]
            int k = k0 + (j >> 1);
            if (k >= 1 && LA[idx] != LA[idx - 1]) sk = 1.f;
        }
        skipf[j] = sk;
    }

    float QB[PD], QL[PD][4];

    float* wsb = ws + (size_t)b * 1024 + role * 512;

    if (role == 0) {
        // ===================== alpha =====================
        // prologue: rows 0..PD-1 into slots 0..PD-1
#pragma unroll
        for (int r = 0; r < PD; ++r) RELOAD(r, r)

        float a[SPL], ac[SPL];
        int E = 0, Eac = 0;
        float fprev = 0.f;
#pragma unroll
        for (int j = 0; j < SPL; ++j) { a[j] = 0.f; ac[j] = 0.f; }
        {   // init from row 0 (slot 0), then immediately repoint slot 0 to row PD
            BUILD_Q(0)
            if (lane == 0) { a[0] = q0; a[1] = q1; }
            RELOAD(0, PD)
        }

        for (int t = 1; t <= m; t += PD) {
            renorm_alpha(a, E, fprev, lane);
            A_STEP(0) A_STEP(1) A_STEP(2) A_STEP(3)
            renorm_alpha(a, E, fprev, lane);
            A_STEP(4) A_STEP(5) A_STEP(6) A_STEP(7)
            renorm_alpha(a, E, fprev, lane);
            A_STEP(8) A_STEP(9) A_STEP(10) A_STEP(11)
        }
#pragma unroll
        for (int j = 0; j < SPL; ++j) wsb[lane * 8 + j] = ac[j];
        ((int*)wsb)[lane * 8 + 7] = Eac;
    } else {
        // ===================== beta =====================
        const int t0 = Tbm1;
        const int nb = t0 - m;             // steps; rows t0 .. m+1
        const int scap = nb - 1;

        // prologue: rows t0-r into slots r
#pragma unroll
        for (int r = 0; r < PD; ++r) RELOAD(r, t0 - r)

        float bb[SPL], bc[SPL];
        int E = 0, Ebc = 0;
        float fnext = 0.f;
#pragma unroll
        for (int j = 0; j < SPL; ++j) {
            int s = s0 + j;
            bb[j] = (s == i1 || s == i2) ? 1.f : 0.f;
            bc[j] = 0.f;
        }
        float skb[SPL];
#pragma unroll
        for (int j = 0; j < 5; ++j) skb[j] = skipf[j + 2];
        skb[5] = (lane == 63) ? 0.f : __shfl_down(skipf[0], 1, 64);
        skb[6] = (lane == 63) ? 0.f : __shfl_down(skipf[1], 1, 64);

        for (int s = 0; s < nb; s += PD) {
            renorm_beta(bb, E, fnext, lane);
            B_STEP(0) B_STEP(1) B_STEP(2) B_STEP(3)
            renorm_beta(bb, E, fnext, lane);
            B_STEP(4) B_STEP(5) B_STEP(6) B_STEP(7)
            renorm_beta(bb, E, fnext, lane);
            B_STEP(8) B_STEP(9) B_STEP(10) B_STEP(11)
        }
#pragma unroll
        for (int j = 0; j < SPL; ++j) wsb[lane * 8 + j] = bc[j];
        ((int*)wsb)[lane * 8 + 7] = Ebc;
    }
}

__global__ void __launch_bounds__(64)
ctc_combine(const float* __restrict__ ws, float* __restrict__ out)
{
    const int b = blockIdx.x;
    const int lane = threadIdx.x;
    const float* wa = ws + (size_t)b * 1024 + lane * 8;
    const float* wb = wa + 512;
    float dot = 0.f;
#pragma unroll
    for (int j = 0; j < SPL; ++j) dot = fmaf(wa[j], wb[j], dot);
    int Ea = ((const int*)wa)[7];
    int Eb = ((const int*)wb)[7];
    float l2 = (dot > 0.f) ? (log2f(dot) + (float)(Ea + Eb)) : -1e30f;
    float M = l2;
#pragma unroll
    for (int d = 1; d < 64; d <<= 1) M = fmaxf(M, __shfl_xor(M, d, 64));
    float S = exp2f(l2 - M);
#pragma unroll
    for (int d = 1; d < 64; d <<= 1) S += __shfl_xor(S, d, 64);
    if (lane == 0)
        out[b] = -(M + log2f(S)) * 0.69314718055994530942f;
}

extern "C" void kernel_launch(void* const* d_in, const int* in_sizes, int n_in,
                              void* d_out, int out_size, void* d_ws, size_t ws_size,
                              hipStream_t stream) {
    (void)n_in; (void)out_size; (void)ws_size;
    const float* y_pred     = (const float*)d_in[0];
    const int*   labels     = (const int*)d_in[1];
    const int*   feat_lens  = (const int*)d_in[2];
    const int*   label_lens = (const int*)d_in[3];
    float* out = (float*)d_out;
    float* ws  = (float*)d_ws;             // 128 * 1024 floats = 512 KB
    const int B = in_sizes[2];             // 128
    ctc_main<<<2 * B, 64, 0, stream>>>(y_pred, labels, feat_lens, label_lens, ws);
    ctc_combine<<<B, 64, 0, stream>>>(ws, out);
}

// Round 5
// 299.377 us; speedup vs baseline: 1.1132x; 1.1132x over previous
//
#include <hip/hip_runtime.h>
#include <math.h>

#define EPSQ 1e-7f
#define TDIM 2000
#define CDIM 128
#define LDIM 200
#define SDIM 401
#define SPL  7
#define SENTE (-(1 << 30))

__device__ __forceinline__ float dpp_shr_f(float x) { // lane i <- lane i-1, lane0 <- 0
    return __int_as_float(__builtin_amdgcn_update_dpp(0, __float_as_int(x), 0x138, 0xf, 0xf, true));
}
__device__ __forceinline__ int dpp_shr_i(int x) {
    return __builtin_amdgcn_update_dpp(0, x, 0x138, 0xf, 0xf, true);
}
__device__ __forceinline__ float dpp_shl_f(float x) { // lane i <- lane i+1, lane63 <- 0
    return __int_as_float(__builtin_amdgcn_update_dpp(0, __float_as_int(x), 0x130, 0xf, 0xf, true));
}
__device__ __forceinline__ int dpp_shl_i(int x) {
    return __builtin_amdgcn_update_dpp(0, x, 0x130, 0xf, 0xf, true);
}

// per-lane block-floating-point renorm (every 4 steps); neighbor = lane-1 (alpha)
__device__ __forceinline__ void renorm_alpha(float a[SPL], int& E, float& fprev, int lane) {
    float mx = fmaxf(fmaxf(fmaxf(a[0], a[1]), fmaxf(a[2], a[3])),
                     fmaxf(fmaxf(a[4], a[5]), a[6]));
    bool zero = (mx == 0.f);
    int e = ((__float_as_int(mx) >> 23) & 0xff) - 127;
    int S_self = zero ? SENTE : (E + e);
    int S1 = dpp_shr_i(S_self);
    if (lane == 0) S1 = SENTE;
    int S2 = dpp_shr_i(S1);
    if (lane == 0) S2 = SENTE;
    int E_new = max(S_self, S1);
    int E_prevnew = max(S1, S2);
    int dg = E - E_new;
    float g = (zero || dg < -126) ? 0.f : __int_as_float((dg + 127) << 23);
#pragma unroll
    for (int j = 0; j < SPL; ++j) a[j] *= g;
    E = E_new;
    int df = E_prevnew - E_new;
    bool fz = (E_prevnew <= SENTE / 2) || (df < -126);
    if (df > 126) df = 126;
    fprev = fz ? 0.f : __int_as_float((df + 127) << 23);
}

// mirror: neighbor = lane+1 (beta)
__device__ __forceinline__ void renorm_beta(float b[SPL], int& E, float& fnext, int lane) {
    float mx = fmaxf(fmaxf(fmaxf(b[0], b[1]), fmaxf(b[2], b[3])),
                     fmaxf(fmaxf(b[4], b[5]), b[6]));
    bool zero = (mx == 0.f);
    int e = ((__float_as_int(mx) >> 23) & 0xff) - 127;
    int S_self = zero ? SENTE : (E + e);
    int S1 = dpp_shl_i(S_self);
    if (lane == 63) S1 = SENTE;
    int S2 = dpp_shl_i(S1);
    if (lane == 63) S2 = SENTE;
    int E_new = max(S_self, S1);
    int E_nextnew = max(S1, S2);
    int dg = E - E_new;
    float g = (zero || dg < -126) ? 0.f : __int_as_float((dg + 127) << 23);
#pragma unroll
    for (int j = 0; j < SPL; ++j) b[j] *= g;
    E = E_new;
    int df = E_nextnew - E_new;
    bool fz = (E_nextnew <= SENTE / 2) || (df < -126);
    if (df > 126) df = 126;
    fnext = fz ? 0.f : __int_as_float((df + 127) << 23);
}

// Gather row (ring slot RSLOT, compile-time) into q[QS][0..6] with parity select.
// EPS was pre-added at staging time.
#define GATHER(QS, RSLOT) do {                                                 \
    float Bv  = ring[(RSLOT) * 128 + 127];                                     \
    float G0  = ring[(RSLOT) * 128 + offL[0]];                                 \
    float G1  = ring[(RSLOT) * 128 + offL[1]];                                 \
    float G2  = ring[(RSLOT) * 128 + offL[2]];                                 \
    float G3  = ring[(RSLOT) * 128 + offL[3]];                                 \
    q[QS][0] = par ? G0 : Bv;  q[QS][1] = par ? Bv : G0;                       \
    q[QS][2] = par ? G1 : Bv;  q[QS][3] = par ? Bv : G1;                       \
    q[QS][4] = par ? G2 : Bv;  q[QS][5] = par ? Bv : G2;                       \
    q[QS][6] = par ? G3 : Bv;                                                  \
} while (0)

// alpha step, t = 16k+1 so all (t+c)&15 / &3 are compile-time from TOFF.
#define A_STEP(TOFF, CAP) do {                                                 \
    {   int rl = t + (TOFF) + 20; rl = (rl > Tbm1) ? Tbm1 : rl;                \
        LD[((TOFF) + 1) & 15] = rp2[(size_t)rl * 64 + lane]; }                 \
    {   float2 w = LD[((TOFF) + 9) & 15];                                      \
        w.x += EPSQ; w.y += EPSQ;                                              \
        *(float2*)&ring[(((TOFF) + 13) & 15) * 128 + lane * 2] = w; }          \
    {   const float* qc = q[((TOFF) + 1) & 3];                                 \
        float p6 = dpp_shr_f(a[6]) * fprev;                                    \
        float p5 = dpp_shr_f(a[5]) * fprev;                                    \
        float n0 = fmaf(skipf[0], p5,   a[0] + p6)   * qc[0];                  \
        float n1 = fmaf(skipf[1], p6,   a[1] + a[0]) * qc[1];                  \
        float n2 = fmaf(skipf[2], a[0], a[2] + a[1]) * qc[2];                  \
        float n3 = fmaf(skipf[3], a[1], a[3] + a[2]) * qc[3];                  \
        float n4 = fmaf(skipf[4], a[2], a[4] + a[3]) * qc[4];                  \
        float n5 = fmaf(skipf[5], a[3], a[5] + a[4]) * qc[5];                  \
        float n6 = fmaf(skipf[6], a[4], a[6] + a[5]) * qc[6];                  \
        a[0]=n0; a[1]=n1; a[2]=n2; a[3]=n3; a[4]=n4; a[5]=n5; a[6]=n6; }       \
    if (CAP) {                                                                 \
        bool cc = (t + (TOFF)) == m;                                           \
        _Pragma("unroll")                                                      \
        for (int j = 0; j < SPL; ++j) ac[j] = cc ? a[j] : ac[j];               \
        Eac = cc ? E : Eac;                                                    \
    }                                                                          \
    GATHER(((TOFF) + 3) & 3, ((TOFF) + 3) & 15);                               \
} while (0);

// beta step, s = 16k.
#define B_STEP(SOFF, CAP) do {                                                 \
    {   int rl = t0 - s - (SOFF) - 20; rl = (rl < 0) ? 0 : rl;                 \
        LD[(SOFF) & 15] = rp2[(size_t)rl * 64 + lane]; }                       \
    {   float2 w = LD[((SOFF) + 8) & 15];                                      \
        w.x += EPSQ; w.y += EPSQ;                                              \
        *(float2*)&ring[(((SOFF) + 12) & 15) * 128 + lane * 2] = w; }          \
    {   const float* qc = q[(SOFF) & 3];                                       \
        float c0 = bb[0]*qc[0], c1 = bb[1]*qc[1], c2 = bb[2]*qc[2];            \
        float c3 = bb[3]*qc[3], c4 = bb[4]*qc[4], c5 = bb[5]*qc[5];            \
        float c6 = bb[6]*qc[6];                                                \
        float cn0 = dpp_shl_f(c0) * fnext;                                     \
        float cn1 = dpp_shl_f(c1) * fnext;                                     \
        bb[0] = fmaf(skb[0], c2, c0 + c1);                                     \
        bb[1] = fmaf(skb[1], c3, c1 + c2);                                     \
        bb[2] = fmaf(skb[2], c4, c2 + c3);                                     \
        bb[3] = fmaf(skb[3], c5, c3 + c4);                                     \
        bb[4] = fmaf(skb[4], c6, c4 + c5);                                     \
        bb[5] = fmaf(skb[5], cn0, c5 + c6);                                    \
        bb[6] = fmaf(skb[6], cn1, c6 + cn0); }                                 \
    if (CAP) {                                                                 \
        bool cc = (s + (SOFF)) == scap;                                        \
        _Pragma("unroll")                                                      \
        for (int j = 0; j < SPL; ++j) bc[j] = cc ? bb[j] : bc[j];              \
        Ebc = cc ? E : Ebc;                                                    \
    }                                                                          \
    GATHER(((SOFF) + 2) & 3, ((SOFF) + 2) & 15);                               \
} while (0);

__global__ void __launch_bounds__(64)
__attribute__((amdgpu_waves_per_eu(1, 1)))
ctc_main(const float* __restrict__ y_pred,
         const int* __restrict__ labels,
         const int* __restrict__ feat_lens,
         const int* __restrict__ label_lens,
         float* __restrict__ ws)           // 1024 floats per batch item
{
    __shared__ float ring[16 * 128];       // 16 rows x 128 classes, 8 KB

    const int b = blockIdx.x >> 1;
    const int role = blockIdx.x & 1;       // 0 = alpha, 1 = beta
    const int lane = threadIdx.x;

    int f = feat_lens[b];
    f = (f + 1) >> 1; f = (f + 1) >> 1;
    const int Tbm1 = f - 1;
    const int m = f >> 1;                  // alpha: steps 1..m; beta: rows Tbm1..m+1
    const int llen = label_lens[b];
    const int i1 = 2 * llen - 1, i2 = 2 * llen;

    const float* ybase = y_pred + (size_t)b * TDIM * CDIM;
    const float2* rp2 = (const float2*)ybase;
    const int* labrow = labels + b * LDIM;

    // ---- per-lane constants ----
    const int s0 = lane * SPL;
    const int k0 = s0 >> 1;
    const bool par = (lane & 1) != 0;      // parity of s0
    int LA[5];
#pragma unroll
    for (int i = 0; i < 5; ++i) {
        int k = k0 - 1 + i;
        if (k < 0) k = 0;
        if (k > LDIM - 1) k = LDIM - 1;
        LA[i] = labrow[k];
    }
    int offL[4];
#pragma unroll
    for (int i = 0; i < 4; ++i) offL[i] = LA[i + 1];

    float skipf[SPL];
#pragma unroll
    for (int j = 0; j < SPL; ++j) {
        int s = s0 + j;
        float sk = 0.f;
        bool emit = (s < SDIM) && ((s & 1) != 0);
        if (emit) {
            int idx = (j >> 1) + 1;
            int k = k0 + (j >> 1);
            if (k >= 1 && LA[idx] != LA[idx - 1]) sk = 1.f;
        }
        skipf[j] = sk;
    }

    float2 LD[16];
    float q[4][SPL];
    float* wsb = ws + (size_t)b * 1024 + role * 512;

    if (role == 0) {
        // ===================== alpha =====================
        // prologue: rows 0..12 staged to ring slots 0..12
#pragma unroll
        for (int r = 0; r < 13; ++r) LD[r] = rp2[(size_t)r * 64 + lane];
#pragma unroll
        for (int r = 0; r < 13; ++r) {
            float2 w = LD[r]; w.x += EPSQ; w.y += EPSQ;
            *(float2*)&ring[r * 128 + lane * 2] = w;
        }
        // rows 13..20 -> LD slots (r+12)&15 = 9..15,0
#pragma unroll
        for (int r = 13; r <= 20; ++r)
            LD[(r + 12) & 15] = rp2[(size_t)r * 64 + lane];

        float a[SPL], ac[SPL];
        int E = 0, Eac = 0;
        float fprev = 0.f;
#pragma unroll
        for (int j = 0; j < SPL; ++j) { a[j] = 0.f; ac[j] = 0.f; }

        GATHER(0, 0);                      // row 0 for init
        if (lane == 0) { a[0] = q[0][0]; a[1] = q[0][1]; }
        GATHER(1, 1);                      // row 1 (consumed at t=1)
        GATHER(2, 2);                      // row 2 (consumed at t=2)

        int t = 1;
        for (; t + 15 < m; t += 16) {      // main: no capture
            renorm_alpha(a, E, fprev, lane);
            A_STEP(0, 0) A_STEP(1, 0) A_STEP(2, 0) A_STEP(3, 0)
            renorm_alpha(a, E, fprev, lane);
            A_STEP(4, 0) A_STEP(5, 0) A_STEP(6, 0) A_STEP(7, 0)
            renorm_alpha(a, E, fprev, lane);
            A_STEP(8, 0) A_STEP(9, 0) A_STEP(10, 0) A_STEP(11, 0)
            renorm_alpha(a, E, fprev, lane);
            A_STEP(12, 0) A_STEP(13, 0) A_STEP(14, 0) A_STEP(15, 0)
        }
        {   // tail: 16 steps with branchless capture (t <= m <= t+15)
            renorm_alpha(a, E, fprev, lane);
            A_STEP(0, 1) A_STEP(1, 1) A_STEP(2, 1) A_STEP(3, 1)
            renorm_alpha(a, E, fprev, lane);
            A_STEP(4, 1) A_STEP(5, 1) A_STEP(6, 1) A_STEP(7, 1)
            renorm_alpha(a, E, fprev, lane);
            A_STEP(8, 1) A_STEP(9, 1) A_STEP(10, 1) A_STEP(11, 1)
            renorm_alpha(a, E, fprev, lane);
            A_STEP(12, 1) A_STEP(13, 1) A_STEP(14, 1) A_STEP(15, 1)
        }
#pragma unroll
        for (int j = 0; j < SPL; ++j) wsb[lane * 8 + j] = ac[j];
        ((int*)wsb)[lane * 8 + 7] = Eac;
    } else {
        // ===================== beta =====================
        const int t0 = Tbm1;
        const int nb = t0 - m;             // steps; rows t0 .. m+1
        const int scap = nb - 1;

        // prologue: rows t0..t0-11 staged to ring slots 0..11
#pragma unroll
        for (int r = 0; r < 12; ++r) LD[r] = rp2[(size_t)(t0 - r) * 64 + lane];
#pragma unroll
        for (int r = 0; r < 12; ++r) {
            float2 w = LD[r]; w.x += EPSQ; w.y += EPSQ;
            *(float2*)&ring[r * 128 + lane * 2] = w;
        }
        // rows t0-12..t0-19 -> LD slots (r-4)&15 = 8..15
#pragma unroll
        for (int r = 12; r <= 19; ++r)
            LD[(r - 4) & 15] = rp2[(size_t)(t0 - r) * 64 + lane];

        float bb[SPL], bc[SPL];
        int E = 0, Ebc = 0;
        float fnext = 0.f;
#pragma unroll
        for (int j = 0; j < SPL; ++j) {
            int s = s0 + j;
            bb[j] = (s == i1 || s == i2) ? 1.f : 0.f;
            bc[j] = 0.f;
        }
        float skb[SPL];
#pragma unroll
        for (int j = 0; j < 5; ++j) skb[j] = skipf[j + 2];
        skb[5] = (lane == 63) ? 0.f : __shfl_down(skipf[0], 1, 64);
        skb[6] = (lane == 63) ? 0.f : __shfl_down(skipf[1], 1, 64);

        GATHER(0, 0);                      // row t0 (consumed at s=0)
        GATHER(1, 1);                      // row t0-1

        int s = 0;
        for (; s + 15 < scap; s += 16) {   // main: no capture
            renorm_beta(bb, E, fnext, lane);
            B_STEP(0, 0) B_STEP(1, 0) B_STEP(2, 0) B_STEP(3, 0)
            renorm_beta(bb, E, fnext, lane);
            B_STEP(4, 0) B_STEP(5, 0) B_STEP(6, 0) B_STEP(7, 0)
            renorm_beta(bb, E, fnext, lane);
            B_STEP(8, 0) B_STEP(9, 0) B_STEP(10, 0) B_STEP(11, 0)
            renorm_beta(bb, E, fnext, lane);
            B_STEP(12, 0) B_STEP(13, 0) B_STEP(14, 0) B_STEP(15, 0)
        }
        {   // tail with branchless capture (s <= scap <= s+15)
            renorm_beta(bb, E, fnext, lane);
            B_STEP(0, 1) B_STEP(1, 1) B_STEP(2, 1) B_STEP(3, 1)
            renorm_beta(bb, E, fnext, lane);
            B_STEP(4, 1) B_STEP(5, 1) B_STEP(6, 1) B_STEP(7, 1)
            renorm_beta(bb, E, fnext, lane);
            B_STEP(8, 1) B_STEP(9, 1) B_STEP(10, 1) B_STEP(11, 1)
            renorm_beta(bb, E, fnext, lane);
            B_STEP(12, 1) B_STEP(13, 1) B_STEP(14, 1) B_STEP(15, 1)
        }
#pragma unroll
        for (int j = 0; j < SPL; ++j) wsb[lane * 8 + j] = bc[j];
        ((int*)wsb)[lane * 8 + 7] = Ebc;
    }
}

__global__ void __launch_bounds__(64)
ctc_combine(const float* __restrict__ ws, float* __restrict__ out)
{
    const int b = blockIdx.x;
    const int lane = threadIdx.x;
    const float* wa = ws + (size_t)b * 1024 + lane * 8;
    const float* wb = wa + 512;
    float dot = 0.f;
#pragma unroll
    for (int j = 0; j < SPL; ++j) dot = fmaf(wa[j], wb[j], dot);
    int Ea = ((const int*)wa)[7];
    int Eb = ((const int*)wb)[7];
    float l2 = (dot > 0.f) ? (log2f(dot) + (float)(Ea + Eb)) : -1e30f;
    float M = l2;
#pragma unroll
    for (int d = 1; d < 64; d <<= 1) M = fmaxf(M, __shfl_xor(M, d, 64));
    float S = exp2f(l2 - M);
#pragma unroll
    for (int d = 1; d < 64; d <<= 1) S += __shfl_xor(S, d, 64);
    if (lane == 0)
        out[b] = -(M + log2f(S)) * 0.69314718055994530942f;
}

extern "C" void kernel_launch(void* const* d_in, const int* in_sizes, int n_in,
                              void* d_out, int out_size, void* d_ws, size_t ws_size,
                              hipStream_t stream) {
    (void)n_in; (void)out_size; (void)ws_size;
    const float* y_pred     = (const float*)d_in[0];
    const int*   labels     = (const int*)d_in[1];
    const int*   feat_lens  = (const int*)d_in[2];
    const int*   label_lens = (const int*)d_in[3];
    float* out = (float*)d_out;
    float* ws  = (float*)d_ws;             // 128 * 1024 floats = 512 KB
    const int B = in_sizes[2];             // 128
    ctc_main<<<2 * B, 64, 0, stream>>>(y_pred, labels, feat_lens, label_lens, ws);
    ctc_combine<<<B, 64, 0, stream>>>(ws, out);
}

// Round 6
// 277.919 us; speedup vs baseline: 1.1992x; 1.0772x over previous
//
#include <hip/hip_runtime.h>
#include <math.h>

#define EPSQ 1e-7f
#define TDIM 2000
#define CDIM 128
#define LDIM 200
#define SDIM 401
#define SPL  7
#define SENTE (-(1 << 30))

__device__ __forceinline__ float dpp_shr_f(float x) { // lane i <- lane i-1, lane0 <- 0
    return __int_as_float(__builtin_amdgcn_update_dpp(0, __float_as_int(x), 0x138, 0xf, 0xf, true));
}
__device__ __forceinline__ int dpp_shr_i(int x) {
    return __builtin_amdgcn_update_dpp(0, x, 0x138, 0xf, 0xf, true);
}
__device__ __forceinline__ float dpp_shl_f(float x) { // lane i <- lane i+1, lane63 <- 0
    return __int_as_float(__builtin_amdgcn_update_dpp(0, __float_as_int(x), 0x130, 0xf, 0xf, true));
}
__device__ __forceinline__ int dpp_shl_i(int x) {
    return __builtin_amdgcn_update_dpp(0, x, 0x130, 0xf, 0xf, true);
}
__device__ __forceinline__ float rdlane63(float x) {
    return __int_as_float(__builtin_amdgcn_readlane(__float_as_int(x), 63));
}

// per-lane block-floating-point renorm (every 4 steps); neighbor = lane-1 (alpha)
__device__ __forceinline__ void renorm_alpha(float a[SPL], int& E, float& fprev, int lane) {
    float mx = fmaxf(fmaxf(fmaxf(a[0], a[1]), fmaxf(a[2], a[3])),
                     fmaxf(fmaxf(a[4], a[5]), a[6]));
    bool zero = (mx == 0.f);
    int e = ((__float_as_int(mx) >> 23) & 0xff) - 127;
    int S_self = zero ? SENTE : (E + e);
    int S1 = dpp_shr_i(S_self);
    if (lane == 0) S1 = SENTE;
    int S2 = dpp_shr_i(S1);
    if (lane == 0) S2 = SENTE;
    int E_new = max(S_self, S1);
    int E_prevnew = max(S1, S2);
    int dg = E - E_new;
    float g = (zero || dg < -126) ? 0.f : __int_as_float((dg + 127) << 23);
#pragma unroll
    for (int j = 0; j < SPL; ++j) a[j] *= g;
    E = E_new;
    int df = E_prevnew - E_new;
    bool fz = (E_prevnew <= SENTE / 2) || (df < -126);
    if (df > 126) df = 126;
    fprev = fz ? 0.f : __int_as_float((df + 127) << 23);
}

// mirror: neighbor = lane+1 (beta)
__device__ __forceinline__ void renorm_beta(float b[SPL], int& E, float& fnext, int lane) {
    float mx = fmaxf(fmaxf(fmaxf(b[0], b[1]), fmaxf(b[2], b[3])),
                     fmaxf(fmaxf(b[4], b[5]), b[6]));
    bool zero = (mx == 0.f);
    int e = ((__float_as_int(mx) >> 23) & 0xff) - 127;
    int S_self = zero ? SENTE : (E + e);
    int S1 = dpp_shl_i(S_self);
    if (lane == 63) S1 = SENTE;
    int S2 = dpp_shl_i(S1);
    if (lane == 63) S2 = SENTE;
    int E_new = max(S_self, S1);
    int E_nextnew = max(S1, S2);
    int dg = E - E_new;
    float g = (zero || dg < -126) ? 0.f : __int_as_float((dg + 127) << 23);
#pragma unroll
    for (int j = 0; j < SPL; ++j) b[j] *= g;
    E = E_new;
    int df = E_nextnew - E_new;
    bool fz = (E_nextnew <= SENTE / 2) || (df < -126);
    if (df > 126) df = 126;
    fnext = fz ? 0.f : __int_as_float((df + 127) << 23);
}

// Gather ring slot RSLOT (compile-time) into q[QS]; blank comes from the VGPR
// ring bvring (no LDS read). EPS pre-added at staging.
#define GATHER(QS, RSLOT) do {                                                 \
    float Bv  = bvring[RSLOT];                                                 \
    float G0  = ring[(RSLOT) * 128 + offL[0]];                                 \
    float G1  = ring[(RSLOT) * 128 + offL[1]];                                 \
    float G2  = ring[(RSLOT) * 128 + offL[2]];                                 \
    float G3  = ring[(RSLOT) * 128 + offL[3]];                                 \
    q[QS][0] = par ? G0 : Bv;  q[QS][1] = par ? Bv : G0;                       \
    q[QS][2] = par ? G1 : Bv;  q[QS][3] = par ? Bv : G1;                       \
    q[QS][4] = par ? G2 : Bv;  q[QS][5] = par ? Bv : G2;                       \
    q[QS][6] = par ? G3 : Bv;                                                  \
} while (0)

// alpha step, t = 16k+1. Step u = t+TOFF:
//  load row u+24 -> LD[(TOFF+9)&15]; stage row u+10 (LD[(TOFF+11)&15]) -> ring;
//  consume q[(TOFF+1)&3]; gather row u+3 (slot (TOFF+4)&15) -> q[TOFF&3].
#define A_STEP(TOFF, CAP) do {                                                 \
    {   int rl = t + (TOFF) + 24; rl = (rl > Tbm1) ? Tbm1 : rl;                \
        LD[((TOFF) + 9) & 15] = rp2[(size_t)rl * 64 + lane]; }                 \
    {   float2 w = LD[((TOFF) + 11) & 15];                                     \
        bvring[((TOFF) + 11) & 15] = rdlane63(w.y) + EPSQ;                     \
        w.x += EPSQ; w.y += EPSQ;                                              \
        *(float2*)&ring[(((TOFF) + 11) & 15) * 128 + lane * 2] = w; }          \
    {   const float* qc = q[((TOFF) + 1) & 3];                                 \
        float p6 = dpp_shr_f(a[6]) * fprev;                                    \
        float p5 = dpp_shr_f(a[5]) * fprev;                                    \
        float n0 = fmaf(skipf[0], p5,   a[0] + p6)   * qc[0];                  \
        float n1 = fmaf(skipf[1], p6,   a[1] + a[0]) * qc[1];                  \
        float n2 = fmaf(skipf[2], a[0], a[2] + a[1]) * qc[2];                  \
        float n3 = fmaf(skipf[3], a[1], a[3] + a[2]) * qc[3];                  \
        float n4 = fmaf(skipf[4], a[2], a[4] + a[3]) * qc[4];                  \
        float n5 = fmaf(skipf[5], a[3], a[5] + a[4]) * qc[5];                  \
        float n6 = fmaf(skipf[6], a[4], a[6] + a[5]) * qc[6];                  \
        a[0]=n0; a[1]=n1; a[2]=n2; a[3]=n3; a[4]=n4; a[5]=n5; a[6]=n6; }       \
    if (CAP) {                                                                 \
        bool cc = (t + (TOFF)) == m;                                           \
        _Pragma("unroll")                                                      \
        for (int j = 0; j < SPL; ++j) ac[j] = cc ? a[j] : ac[j];               \
        Eac = cc ? E : Eac;                                                    \
    }                                                                          \
    GATHER((TOFF) & 3, ((TOFF) + 4) & 15);                                     \
} while (0);

// beta step, s = 16k. Step index u = s+SOFF (row t0-u):
//  load idx u+24 -> LD[(SOFF+8)&15]; stage idx u+10 (LD[(SOFF+10)&15]) -> ring;
//  consume q[SOFF&3]; gather idx u+3 (slot (SOFF+3)&15) -> q[(SOFF+3)&3].
#define B_STEP(SOFF, CAP) do {                                                 \
    {   int rl = t0 - s - (SOFF) - 24; rl = (rl < 0) ? 0 : rl;                 \
        LD[((SOFF) + 8) & 15] = rp2[(size_t)rl * 64 + lane]; }                 \
    {   float2 w = LD[((SOFF) + 10) & 15];                                     \
        bvring[((SOFF) + 10) & 15] = rdlane63(w.y) + EPSQ;                     \
        w.x += EPSQ; w.y += EPSQ;                                              \
        *(float2*)&ring[(((SOFF) + 10) & 15) * 128 + lane * 2] = w; }          \
    {   const float* qc = q[(SOFF) & 3];                                       \
        float c0 = bb[0]*qc[0], c1 = bb[1]*qc[1], c2 = bb[2]*qc[2];            \
        float c3 = bb[3]*qc[3], c4 = bb[4]*qc[4], c5 = bb[5]*qc[5];            \
        float c6 = bb[6]*qc[6];                                                \
        float cn0 = dpp_shl_f(c0) * fnext;                                     \
        float cn1 = dpp_shl_f(c1) * fnext;                                     \
        bb[0] = fmaf(skb[0], c2, c0 + c1);                                     \
        bb[1] = fmaf(skb[1], c3, c1 + c2);                                     \
        bb[2] = fmaf(skb[2], c4, c2 + c3);                                     \
        bb[3] = fmaf(skb[3], c5, c3 + c4);                                     \
        bb[4] = fmaf(skb[4], c6, c4 + c5);                                     \
        bb[5] = fmaf(skb[5], cn0, c5 + c6);                                    \
        bb[6] = fmaf(skb[6], cn1, c6 + cn0); }                                 \
    if (CAP) {                                                                 \
        bool cc = (s + (SOFF)) == scap;                                        \
        _Pragma("unroll")                                                      \
        for (int j = 0; j < SPL; ++j) bc[j] = cc ? bb[j] : bc[j];              \
        Ebc = cc ? E : Ebc;                                                    \
    }                                                                          \
    GATHER(((SOFF) + 3) & 3, ((SOFF) + 3) & 15);                               \
} while (0);

__global__ void __launch_bounds__(64)
__attribute__((amdgpu_waves_per_eu(1, 1)))
ctc_main(const float* __restrict__ y_pred,
         const int* __restrict__ labels,
         const int* __restrict__ feat_lens,
         const int* __restrict__ label_lens,
         float* __restrict__ ws)           // 1024 floats per batch item
{
    __shared__ float ring[16 * 128];       // 16 rows x 128 classes, 8 KB

    const int b = blockIdx.x >> 1;
    const int role = blockIdx.x & 1;       // 0 = alpha, 1 = beta
    const int lane = threadIdx.x;

    int f = feat_lens[b];
    f = (f + 1) >> 1; f = (f + 1) >> 1;
    const int Tbm1 = f - 1;
    const int m = f >> 1;                  // alpha: steps 1..m; beta: rows Tbm1..m+1
    const int llen = label_lens[b];
    const int i1 = 2 * llen - 1, i2 = 2 * llen;

    const float* ybase = y_pred + (size_t)b * TDIM * CDIM;
    const float2* rp2 = (const float2*)ybase;
    const int* labrow = labels + b * LDIM;

    // ---- per-lane constants ----
    const int s0 = lane * SPL;
    const int k0 = s0 >> 1;
    const bool par = (lane & 1) != 0;      // parity of s0
    int LA[5];
#pragma unroll
    for (int i = 0; i < 5; ++i) {
        int k = k0 - 1 + i;
        if (k < 0) k = 0;
        if (k > LDIM - 1) k = LDIM - 1;
        LA[i] = labrow[k];
    }
    int offL[4];
#pragma unroll
    for (int i = 0; i < 4; ++i) offL[i] = LA[i + 1];

    float skipf[SPL];
#pragma unroll
    for (int j = 0; j < SPL; ++j) {
        int s = s0 + j;
        float sk = 0.f;
        bool emit = (s < SDIM) && ((s & 1) != 0);
        if (emit) {
            int idx = (j >> 1) + 1;
            int k = k0 + (j >> 1);
            if (k >= 1 && LA[idx] != LA[idx - 1]) sk = 1.f;
        }
        skipf[j] = sk;
    }

    float2 LD[16];
    float bvring[16];
    float q[4][SPL];
    float* wsb = ws + (size_t)b * 1024 + role * 512;

    if (role == 0) {
        // ===================== alpha =====================
        // stage rows 0..10 -> ring slots 0..10 (+ bvring)
#pragma unroll
        for (int r = 0; r < 11; ++r) {
            int rl = (r > Tbm1) ? Tbm1 : r;
            LD[r] = rp2[(size_t)rl * 64 + lane];
        }
#pragma unroll
        for (int r = 0; r < 11; ++r) {
            float2 w = LD[r];
            bvring[r] = rdlane63(w.y) + EPSQ;
            w.x += EPSQ; w.y += EPSQ;
            *(float2*)&ring[r * 128 + lane * 2] = w;
        }
        // rows 11..24 -> LD[r&15] (written at steps 1..14)
#pragma unroll
        for (int r = 11; r <= 24; ++r) {
            int rl = (r > Tbm1) ? Tbm1 : r;
            LD[r & 15] = rp2[(size_t)rl * 64 + lane];
        }

        float a[SPL], ac[SPL];
        int E = 0, Eac = 0;
        float fprev = 0.f;
#pragma unroll
        for (int j = 0; j < SPL; ++j) { a[j] = 0.f; ac[j] = 0.f; }

        GATHER(0, 0);                      // row 0 for init (q[0] reused at step 1)
        if (lane == 0) { a[0] = q[0][0]; a[1] = q[0][1]; }
        GATHER(1, 1);                      // row 1 (consumed at t=1)
        GATHER(2, 2);                      // row 2
        GATHER(3, 3);                      // row 3

        int t = 1;
        for (; t + 15 < m; t += 16) {      // main: no capture
            renorm_alpha(a, E, fprev, lane);
            A_STEP(0, 0) A_STEP(1, 0) A_STEP(2, 0) A_STEP(3, 0)
            renorm_alpha(a, E, fprev, lane);
            A_STEP(4, 0) A_STEP(5, 0) A_STEP(6, 0) A_STEP(7, 0)
            renorm_alpha(a, E, fprev, lane);
            A_STEP(8, 0) A_STEP(9, 0) A_STEP(10, 0) A_STEP(11, 0)
            renorm_alpha(a, E, fprev, lane);
            A_STEP(12, 0) A_STEP(13, 0) A_STEP(14, 0) A_STEP(15, 0)
        }
        {   // tail: 16 steps with branchless capture (t <= m <= t+15)
            renorm_alpha(a, E, fprev, lane);
            A_STEP(0, 1) A_STEP(1, 1) A_STEP(2, 1) A_STEP(3, 1)
            renorm_alpha(a, E, fprev, lane);
            A_STEP(4, 1) A_STEP(5, 1) A_STEP(6, 1) A_STEP(7, 1)
            renorm_alpha(a, E, fprev, lane);
            A_STEP(8, 1) A_STEP(9, 1) A_STEP(10, 1) A_STEP(11, 1)
            renorm_alpha(a, E, fprev, lane);
            A_STEP(12, 1) A_STEP(13, 1) A_STEP(14, 1) A_STEP(15, 1)
        }
#pragma unroll
        for (int j = 0; j < SPL; ++j) wsb[lane * 8 + j] = ac[j];
        ((int*)wsb)[lane * 8 + 7] = Eac;
    } else {
        // ===================== beta =====================
        const int t0 = Tbm1;
        const int nb = t0 - m;             // steps; rows t0 .. m+1
        const int scap = nb - 1;

        // stage idx 0..10 (rows t0..t0-10) -> ring slots 0..10 (+ bvring)
#pragma unroll
        for (int r = 0; r < 11; ++r) {
            int rl = t0 - r; rl = (rl < 0) ? 0 : rl;
            LD[r] = rp2[(size_t)rl * 64 + lane];
        }
#pragma unroll
        for (int r = 0; r < 11; ++r) {
            float2 w = LD[r];
            bvring[r] = rdlane63(w.y) + EPSQ;
            w.x += EPSQ; w.y += EPSQ;
            *(float2*)&ring[r * 128 + lane * 2] = w;
        }
        // idx 11..24 -> LD[r&15]
#pragma unroll
        for (int r = 11; r <= 24; ++r) {
            int rl = t0 - r; rl = (rl < 0) ? 0 : rl;
            LD[r & 15] = rp2[(size_t)rl * 64 + lane];
        }

        float bb[SPL], bc[SPL];
        int E = 0, Ebc = 0;
        float fnext = 0.f;
#pragma unroll
        for (int j = 0; j < SPL; ++j) {
            int s = s0 + j;
            bb[j] = (s == i1 || s == i2) ? 1.f : 0.f;
            bc[j] = 0.f;
        }
        float skb[SPL];
#pragma unroll
        for (int j = 0; j < 5; ++j) skb[j] = skipf[j + 2];
        skb[5] = (lane == 63) ? 0.f : __shfl_down(skipf[0], 1, 64);
        skb[6] = (lane == 63) ? 0.f : __shfl_down(skipf[1], 1, 64);

        GATHER(0, 0);                      // idx 0 (row t0, consumed at s=0)
        GATHER(1, 1);                      // idx 1
        GATHER(2, 2);                      // idx 2

        int s = 0;
        for (; s + 15 < scap; s += 16) {   // main: no capture
            renorm_beta(bb, E, fnext, lane);
            B_STEP(0, 0) B_STEP(1, 0) B_STEP(2, 0) B_STEP(3, 0)
            renorm_beta(bb, E, fnext, lane);
            B_STEP(4, 0) B_STEP(5, 0) B_STEP(6, 0) B_STEP(7, 0)
            renorm_beta(bb, E, fnext, lane);
            B_STEP(8, 0) B_STEP(9, 0) B_STEP(10, 0) B_STEP(11, 0)
            renorm_beta(bb, E, fnext, lane);
            B_STEP(12, 0) B_STEP(13, 0) B_STEP(14, 0) B_STEP(15, 0)
        }
        {   // tail with branchless capture (s <= scap <= s+15)
            renorm_beta(bb, E, fnext, lane);
            B_STEP(0, 1) B_STEP(1, 1) B_STEP(2, 1) B_STEP(3, 1)
            renorm_beta(bb, E, fnext, lane);
            B_STEP(4, 1) B_STEP(5, 1) B_STEP(6, 1) B_STEP(7, 1)
            renorm_beta(bb, E, fnext, lane);
            B_STEP(8, 1) B_STEP(9, 1) B_STEP(10, 1) B_STEP(11, 1)
            renorm_beta(bb, E, fnext, lane);
            B_STEP(12, 1) B_STEP(13, 1) B_STEP(14, 1) B_STEP(15, 1)
        }
#pragma unroll
        for (int j = 0; j < SPL; ++j) wsb[lane * 8 + j] = bc[j];
        ((int*)wsb)[lane * 8 + 7] = Ebc;
    }
}

__global__ void __launch_bounds__(64)
ctc_combine(const float* __restrict__ ws, float* __restrict__ out)
{
    const int b = blockIdx.x;
    const int lane = threadIdx.x;
    const float* wa = ws + (size_t)b * 1024 + lane * 8;
    const float* wb = wa + 512;
    float dot = 0.f;
#pragma unroll
    for (int j = 0; j < SPL; ++j) dot = fmaf(wa[j], wb[j], dot);
    int Ea = ((const int*)wa)[7];
    int Eb = ((const int*)wb)[7];
    float l2 = (dot > 0.f) ? (log2f(dot) + (float)(Ea + Eb)) : -1e30f;
    float M = l2;
#pragma unroll
    for (int d = 1; d < 64; d <<= 1) M = fmaxf(M, __shfl_xor(M, d, 64));
    float S = exp2f(l2 - M);
#pragma unroll
    for (int d = 1; d < 64; d <<= 1) S += __shfl_xor(S, d, 64);
    if (lane == 0)
        out[b] = -(M + log2f(S)) * 0.69314718055994530942f;
}

extern "C" void kernel_launch(void* const* d_in, const int* in_sizes, int n_in,
                              void* d_out, int out_size, void* d_ws, size_t ws_size,
                              hipStream_t stream) {
    (void)n_in; (void)out_size; (void)ws_size;
    const float* y_pred     = (const float*)d_in[0];
    const int*   labels     = (const int*)d_in[1];
    const int*   feat_lens  = (const int*)d_in[2];
    const int*   label_lens = (const int*)d_in[3];
    float* out = (float*)d_out;
    float* ws  = (float*)d_ws;             // 128 * 1024 floats = 512 KB
    const int B = in_sizes[2];             // 128
    ctc_main<<<2 * B, 64, 0, stream>>>(y_pred, labels, feat_lens, label_lens, ws);
    ctc_combine<<<B, 64, 0, stream>>>(ws, out);
}